// Round 9
// baseline (251.716 us; speedup 1.0000x reference)
//
#include <hip/hip_runtime.h>
#include <hip/hip_bf16.h>

typedef __bf16 v8bf16 __attribute__((ext_vector_type(8)));
typedef __bf16 bf16x4 __attribute__((ext_vector_type(4)));
typedef float  f32x4  __attribute__((ext_vector_type(4)));
typedef float  f32x16 __attribute__((ext_vector_type(16)));

#define D_MODEL 2048
#define S_LEN   2048
#define NHEADS  32
#define NGROUPS 8
#define DK      64
#define NTOK    4096   // B*S
#define NQKV    3072   // 2048 + 512 + 512
// 0.125 (1/sqrt(64)) * log2(e): softmax done in base-2 domain
#define QSCALE  0.18033688011112042f

__device__ __forceinline__ void lds_load16(const void* g, void* l) {
  __builtin_amdgcn_global_load_lds(
      (__attribute__((address_space(1))) unsigned int*)g,
      (__attribute__((address_space(3))) unsigned int*)l, 16, 0, 0);
}

// ---------------- fp32 -> bf16 elementwise ----------------
__global__ __launch_bounds__(256)
void cvt_f32_bf16(const float* __restrict__ in, __bf16* __restrict__ out, int n) {
  int i = (blockIdx.x * 256 + threadIdx.x) * 4;
  if (i >= n) return;
  float4 v = *(const float4*)(in + i);
  bf16x4 o = { (__bf16)v.x, (__bf16)v.y, (__bf16)v.z, (__bf16)v.w };
  *(bf16x4*)(out + i) = o;
}

// ---------------- fp32 [R][C] -> bf16 [C][R] transpose-convert ----------------
__global__ __launch_bounds__(256)
void transpose_cvt(const float* __restrict__ in, __bf16* __restrict__ out, int R, int C) {
  __shared__ float tile[32][33];
  int tx = threadIdx.x, ty = threadIdx.y;
  int c0 = blockIdx.x * 32, r0 = blockIdx.y * 32;
#pragma unroll
  for (int j = 0; j < 4; j++)
    tile[ty + 8 * j][tx] = in[(size_t)(r0 + ty + 8 * j) * C + c0 + tx];
  __syncthreads();
#pragma unroll
  for (int j = 0; j < 4; j++)
    out[(size_t)(c0 + ty + 8 * j) * R + r0 + tx] = (__bf16)tile[tx][ty + 8 * j];
}

// ---------------- bf16 [R][Csub] (ld=ldin) -> bf16 [Csub][R] (ld=ldout) ----------------
__global__ __launch_bounds__(256)
void transpose_bf16(const __bf16* __restrict__ in, __bf16* __restrict__ out,
                    int R, int C, int ldin, int ldout) {
  __shared__ __bf16 tile[32][33];
  int tx = threadIdx.x, ty = threadIdx.y;
  int c0 = blockIdx.x * 32, r0 = blockIdx.y * 32;
#pragma unroll
  for (int j = 0; j < 4; j++)
    tile[ty + 8 * j][tx] = in[(size_t)(r0 + ty + 8 * j) * ldin + c0 + tx];
  __syncthreads();
#pragma unroll
  for (int j = 0; j < 4; j++)
    out[(size_t)(c0 + ty + 8 * j) * ldout + r0 + tx] = tile[tx][ty + 8 * j];
}

// ---------------- GEMM: C[M][N] = A[M][K] * BT[N][K]^T + bias ----------------
template <int MODE>
__global__ __launch_bounds__(256, 2)
void gemm_bt(const __bf16* __restrict__ A, const __bf16* __restrict__ BT,
             const float* __restrict__ b0, const float* __restrict__ b1,
             const float* __restrict__ b2,
             __bf16* __restrict__ Cb, float* __restrict__ Cf,
             int M, int N, int K) {
  __shared__ __bf16 As[128 * 32];
  __shared__ __bf16 Bs[128 * 32];
  const int t = threadIdx.x;
  const int lane = t & 63, w = t >> 6;
  const int lr = lane & 15, lg = lane >> 4;
  // XCD-aware block swizzle (grid size is a multiple of 8)
  const int gx = gridDim.x;
  const int flat = blockIdx.y * gx + blockIdx.x;
  const int cpx = (gx * gridDim.y) >> 3;
  const int sb = (flat & 7) * cpx + (flat >> 3);
  const int m0 = (sb / gx) * 128, n0 = (sb % gx) * 128;
  const int rm = (w >> 1) * 64, cn = (w & 1) * 64;
  const int srow = t >> 2, scol = (t & 3) * 8;

  const f32x4 fz = {0.f, 0.f, 0.f, 0.f};
  f32x4 acc[4][4];
#pragma unroll
  for (int mi = 0; mi < 4; mi++)
#pragma unroll
    for (int ni = 0; ni < 4; ni++) acc[mi][ni] = fz;

  for (int kt = 0; kt < K; kt += 32) {
    __syncthreads();
    lds_load16(A + (size_t)(m0 + srow) * K + kt + scol, As + w * 512);
    lds_load16(A + (size_t)(m0 + 64 + srow) * K + kt + scol, As + 2048 + w * 512);
    lds_load16(BT + (size_t)(n0 + srow) * K + kt + scol, Bs + w * 512);
    lds_load16(BT + (size_t)(n0 + 64 + srow) * K + kt + scol, Bs + 2048 + w * 512);
    __syncthreads();
    v8bf16 af[4], bfr[4];
#pragma unroll
    for (int i = 0; i < 4; i++)
      af[i] = *(const v8bf16*)&As[(rm + i * 16 + lr) * 32 + lg * 8];
#pragma unroll
    for (int i = 0; i < 4; i++)
      bfr[i] = *(const v8bf16*)&Bs[(cn + i * 16 + lr) * 32 + lg * 8];
#pragma unroll
    for (int mi = 0; mi < 4; mi++)
#pragma unroll
      for (int ni = 0; ni < 4; ni++)
        acc[mi][ni] = __builtin_amdgcn_mfma_f32_16x16x32_bf16(af[mi], bfr[ni], acc[mi][ni], 0, 0, 0);
  }

#pragma unroll
  for (int ni = 0; ni < 4; ni++) {
    int col = n0 + cn + ni * 16 + lr;
    float bias, scale = 1.0f;
    if (MODE == 0) {
      if (col < 2048)      { bias = b0[col];        scale = QSCALE; }
      else if (col < 2560) { bias = b1[col - 2048]; }
      else                 { bias = b2[col - 2560]; }
    } else {
      bias = b0[col];
    }
#pragma unroll
    for (int mi = 0; mi < 4; mi++)
#pragma unroll
      for (int r = 0; r < 4; r++) {
        int row = m0 + rm + mi * 16 + lg * 4 + r;
        float v = acc[mi][ni][r] + bias;
        if (MODE == 0) Cb[(size_t)row * N + col] = (__bf16)(v * scale);
        else           Cf[(size_t)row * N + col] = v;
      }
  }
}

// ---------------- GQA flash attention (8 waves, 32x32x16 MFMA, triple-buffer) ----------------
// Swapped QK^T at 32x32: C[key][q], col=lane&31=q, row=(reg&3)+8*(reg>>2)+4*(lane>>5)=key.
// 20 MFMA/tile/wave (vs 36 at 16x16), same FLOPs. Fixed-scale softmax (no max tracking).
// Row-sum via ones-MFMA. Pipeline: [vmcnt(2); barrier; stage(kt+2); compute(kt)].
// QKV: [4096][3072] bf16 (Q pre-scaled by QSCALE incl. log2e, K at 2048, V at 2560)
// VT:  [512][4096] bf16  (VT[g*64+d][b*2048+s])
// ctx: [4096][2048] bf16 out
__global__ __launch_bounds__(512, 2)
void attn_kernel(const __bf16* __restrict__ QKV, const __bf16* __restrict__ VT,
                 __bf16* __restrict__ ctx) {
  // 68KB: 3 K/V buffers (each K:0..4095, V:4096..8191), P: per-wave [32 q][40 keys] at 24576+w*1280
  __shared__ __bf16 smem[34816];
  const int t = threadIdx.x;
  const int lane = t & 63, w = t >> 6;
  const int lc = lane & 31, hi = lane >> 5;
  // XCD-aware swizzle: same head's q-tiles cluster on one XCD (grid 512 = 8*64)
  const int flat = blockIdx.y * 8 + blockIdx.x;
  const int swz = (flat & 7) * 64 + (flat >> 3);
  const int qt = swz & 7, bh = swz >> 3;
  const int b = bh >> 5, h = bh & 31, g = h >> 2;
  const int q0 = qt * 256;
  // pre-swizzled source column for staging (inverse of the XOR used on reads)
  const int scol = (((t & 7) ^ ((t >> 3) & 7)) << 3);

  // Q B-fragments straight from global: lane holds Q[q = lc][dk = m*16 + hi*8 .. +8]
  v8bf16 qb[4];
#pragma unroll
  for (int m = 0; m < 4; m++)
    qb[m] = *(const v8bf16*)(QKV +
        (size_t)(b * S_LEN + q0 + w * 32 + lc) * NQKV + h * DK + m * 16 + hi * 8);

  // staging sources (thread t covers row t>>3, 8 cols at scol), advanced per stage
  const __bf16* kp = QKV + (size_t)(b * S_LEN + (t >> 3)) * NQKV + D_MODEL + g * DK + scol;
  const __bf16* vp = VT + (size_t)(g * DK + (t >> 3)) * NTOK + b * S_LEN + scol;

  auto stage = [&](__bf16* buf) {
    lds_load16(kp, buf + t * 8);
    lds_load16(vp, buf + 4096 + t * 8);
    kp += (size_t)64 * NQKV;
    vp += 64;
  };

  __bf16* bufA = smem;
  __bf16* bufB = smem + 8192;
  __bf16* bufC = smem + 16384;

  // prologue: tiles 0,1 in flight (4 outstanding vmem ops per wave)
  stage(bufA);
  stage(bufB);

  // loop-invariant swizzled column offsets, shared by K and V fragment reads
  // (rows are lc-based; (row&7) == (lc&7) for all row groups used)
  int coloff[4];
#pragma unroll
  for (int m = 0; m < 4; m++)
    coloff[m] = (m * 16 + hi * 8) ^ ((lc & 7) << 3);

  __bf16* Pw = smem + 24576 + w * 1280;       // [32 q][40 keys], 32-key half reuse
  __bf16* ppw = Pw + lc * 40 + hi * 4;        // write base: row q=lc, col 4*hi + 8u
  const __bf16* ppr = Pw + lc * 40 + hi * 8;  // read base:  row q=lc, col 8*hi + 16*k4

  const __bf16 one1 = (__bf16)1.0f;
  const v8bf16 ones = { one1, one1, one1, one1, one1, one1, one1, one1 };
  const f32x16 fz16 = {0.f,0.f,0.f,0.f,0.f,0.f,0.f,0.f,0.f,0.f,0.f,0.f,0.f,0.f,0.f,0.f};
  f32x16 o[2], osum;
  o[0] = fz16; o[1] = fz16; osum = fz16;

  auto compute = [&](const __bf16* Kb) {
    const __bf16* kb0 = Kb + lc * 64;          // K rows: tile0 = lc, tile1 = 32+lc
    const __bf16* vb0 = Kb + 4096 + lc * 64;   // V rows: d = dt*32 + lc
    // QK^T swapped, 32x32x16: st[t2] = C[key = t2*32 + crow][q = lc]
    f32x16 st[2];
    st[0] = fz16; st[1] = fz16;
    __builtin_amdgcn_s_setprio(1);
#pragma unroll
    for (int m = 0; m < 4; m++) {
      v8bf16 ka0 = *(const v8bf16*)(kb0 + coloff[m]);
      v8bf16 ka1 = *(const v8bf16*)(kb0 + 2048 + coloff[m]);
      st[0] = __builtin_amdgcn_mfma_f32_32x32x16_bf16(ka0, qb[m], st[0], 0, 0, 0);
      st[1] = __builtin_amdgcn_mfma_f32_32x32x16_bf16(ka1, qb[m], st[1], 0, 0, 0);
    }
    __builtin_amdgcn_s_setprio(0);

    // per 32-key half: exp2 (packed 4s, key = (r&3)+8*(r>>2)+4*hi), P write,
    // b128 read-back as PV A-frags, PV + ones-MFMA row-sum
#pragma unroll
    for (int t2 = 0; t2 < 2; t2++) {
#pragma unroll
      for (int u = 0; u < 4; u++) {
        bf16x4 pk = { (__bf16)exp2f(st[t2][4 * u + 0]), (__bf16)exp2f(st[t2][4 * u + 1]),
                      (__bf16)exp2f(st[t2][4 * u + 2]), (__bf16)exp2f(st[t2][4 * u + 3]) };
        *(bf16x4*)(ppw + u * 8) = pk;
      }
      v8bf16 pa0 = *(const v8bf16*)(ppr);
      v8bf16 pa1 = *(const v8bf16*)(ppr + 16);
      __builtin_amdgcn_s_setprio(1);
#pragma unroll
      for (int k4 = 0; k4 < 2; k4++) {
        v8bf16 pa = k4 ? pa1 : pa0;
        v8bf16 vq0 = *(const v8bf16*)(vb0 + coloff[t2 * 2 + k4]);
        v8bf16 vq1 = *(const v8bf16*)(vb0 + 2048 + coloff[t2 * 2 + k4]);
        o[0] = __builtin_amdgcn_mfma_f32_32x32x16_bf16(pa, vq0, o[0], 0, 0, 0);
        o[1] = __builtin_amdgcn_mfma_f32_32x32x16_bf16(pa, vq1, o[1], 0, 0, 0);
        osum = __builtin_amdgcn_mfma_f32_32x32x16_bf16(pa, ones, osum, 0, 0, 0);
      }
      __builtin_amdgcn_s_setprio(0);
    }
  };

  // main pipeline: tiles 0..30; cur = tile kt, nxt = kt+1 (in flight), fre = staging target
  __bf16* cur = bufA;
  __bf16* nxt = bufB;
  __bf16* fre = bufC;
  for (int kt = 0; kt < 31; kt++) {
    asm volatile("s_waitcnt vmcnt(2)" ::: "memory");  // this wave's tile-kt loads landed
    __builtin_amdgcn_s_barrier();                     // => all waves' tile-kt loads landed
    __builtin_amdgcn_sched_barrier(0);
    if (kt < 30) stage(fre);  // overwrite buffer last read at kt-1 (WAR-safe post-barrier)
    compute(cur);
    __bf16* tmp = cur; cur = nxt; nxt = fre; fre = tmp;
  }
  // final tile 31
  asm volatile("s_waitcnt vmcnt(0)" ::: "memory");
  __builtin_amdgcn_s_barrier();
  __builtin_amdgcn_sched_barrier(0);
  compute(cur);

  // epilogue: osum rows match o rows (q = (r&3)+8*(r>>2)+4*hi); no shuffles
#pragma unroll
  for (int r = 0; r < 16; r++) {
    float inv = 1.0f / osum[r];
    int row = b * S_LEN + q0 + w * 32 + (r & 3) + 8 * (r >> 2) + 4 * hi;
    ctx[(size_t)row * D_MODEL + h * DK + lc]      = (__bf16)(o[0][r] * inv);
    ctx[(size_t)row * D_MODEL + h * DK + 32 + lc] = (__bf16)(o[1][r] * inv);
  }
}

extern "C" void kernel_launch(void* const* d_in, const int* in_sizes, int n_in,
                              void* d_out, int out_size, void* d_ws, size_t ws_size,
                              hipStream_t stream) {
  (void)in_sizes; (void)n_in; (void)out_size; (void)ws_size;
  const float* x  = (const float*)d_in[0];
  const float* wq = (const float*)d_in[1];
  const float* bq = (const float*)d_in[2];
  const float* wk = (const float*)d_in[3];
  const float* bk = (const float*)d_in[4];
  const float* wv = (const float*)d_in[5];
  const float* bv = (const float*)d_in[6];
  const float* wo = (const float*)d_in[7];
  const float* bo = (const float*)d_in[8];

  char* ws = (char*)d_ws;
  __bf16* xb    = (__bf16*)(ws);                 // [4096][2048]   16 MB
  __bf16* wqkvT = (__bf16*)(ws + 16777216);      // [3072][2048]   12 MB
  __bf16* woT   = (__bf16*)(ws + 29360128);      // [2048][2048]    8 MB
  __bf16* QKVb  = (__bf16*)(ws + 37748736);      // [4096][3072]   24 MB
  __bf16* VbT   = (__bf16*)(ws + 62914560);      // [512][4096]     4 MB
  __bf16* ctx   = (__bf16*)(ws + 67108864);      // [4096][2048]   16 MB

  dim3 tb(32, 8);
  cvt_f32_bf16<<<8192, 256, 0, stream>>>(x, xb, NTOK * D_MODEL);
  transpose_cvt<<<dim3(64, 64), tb, 0, stream>>>(wq, wqkvT, 2048, 2048);
  transpose_cvt<<<dim3(16, 64), tb, 0, stream>>>(wk, wqkvT + 2048 * 2048, 2048, 512);
  transpose_cvt<<<dim3(16, 64), tb, 0, stream>>>(wv, wqkvT + 2560 * 2048, 2048, 512);
  transpose_cvt<<<dim3(64, 64), tb, 0, stream>>>(wo, woT, 2048, 2048);

  gemm_bt<0><<<dim3(24, 32), 256, 0, stream>>>(xb, wqkvT, bq, bk, bv,
                                               QKVb, nullptr, NTOK, NQKV, 2048);
  transpose_bf16<<<dim3(16, 128), tb, 0, stream>>>(QKVb + 2560, VbT, 4096, 512, 3072, 4096);
  attn_kernel<<<dim3(8, 64), 512, 0, stream>>>(QKVb, VbT, ctx);
  gemm_bt<1><<<dim3(16, 32), 256, 0, stream>>>(ctx, woT, bo, nullptr, nullptr,
                                               nullptr, (float*)d_out, NTOK, 2048, 2048);
}

// Round 10
// 251.081 us; speedup vs baseline: 1.0025x; 1.0025x over previous
//
#include <hip/hip_runtime.h>
#include <hip/hip_bf16.h>

typedef __bf16 v8bf16 __attribute__((ext_vector_type(8)));
typedef __bf16 bf16x4 __attribute__((ext_vector_type(4)));
typedef float  f32x4  __attribute__((ext_vector_type(4)));

#define D_MODEL 2048
#define S_LEN   2048
#define NHEADS  32
#define NGROUPS 8
#define DK      64
#define NTOK    4096   // B*S
#define NQKV    3072   // 2048 + 512 + 512
// 0.125 (1/sqrt(64)) * log2(e): softmax done in base-2 domain
#define QSCALE  0.18033688011112042f

__device__ __forceinline__ void lds_load16(const void* g, void* l) {
  __builtin_amdgcn_global_load_lds(
      (__attribute__((address_space(1))) unsigned int*)g,
      (__attribute__((address_space(3))) unsigned int*)l, 16, 0, 0);
}

// ---------------- fp32 -> bf16 elementwise ----------------
__global__ __launch_bounds__(256)
void cvt_f32_bf16(const float* __restrict__ in, __bf16* __restrict__ out, int n) {
  int i = (blockIdx.x * 256 + threadIdx.x) * 4;
  if (i >= n) return;
  float4 v = *(const float4*)(in + i);
  bf16x4 o = { (__bf16)v.x, (__bf16)v.y, (__bf16)v.z, (__bf16)v.w };
  *(bf16x4*)(out + i) = o;
}

// ---------------- fp32 [R][C] -> bf16 [C][R] transpose-convert ----------------
__global__ __launch_bounds__(256)
void transpose_cvt(const float* __restrict__ in, __bf16* __restrict__ out, int R, int C) {
  __shared__ float tile[32][33];
  int tx = threadIdx.x, ty = threadIdx.y;
  int c0 = blockIdx.x * 32, r0 = blockIdx.y * 32;
#pragma unroll
  for (int j = 0; j < 4; j++)
    tile[ty + 8 * j][tx] = in[(size_t)(r0 + ty + 8 * j) * C + c0 + tx];
  __syncthreads();
#pragma unroll
  for (int j = 0; j < 4; j++)
    out[(size_t)(c0 + ty + 8 * j) * R + r0 + tx] = (__bf16)tile[tx][ty + 8 * j];
}

// ---------------- bf16 [R][Csub] (ld=ldin) -> bf16 [Csub][R] (ld=ldout) ----------------
__global__ __launch_bounds__(256)
void transpose_bf16(const __bf16* __restrict__ in, __bf16* __restrict__ out,
                    int R, int C, int ldin, int ldout) {
  __shared__ __bf16 tile[32][33];
  int tx = threadIdx.x, ty = threadIdx.y;
  int c0 = blockIdx.x * 32, r0 = blockIdx.y * 32;
#pragma unroll
  for (int j = 0; j < 4; j++)
    tile[ty + 8 * j][tx] = in[(size_t)(r0 + ty + 8 * j) * ldin + c0 + tx];
  __syncthreads();
#pragma unroll
  for (int j = 0; j < 4; j++)
    out[(size_t)(c0 + ty + 8 * j) * ldout + r0 + tx] = tile[tx][ty + 8 * j];
}

// ---------------- GEMM: C[M][N] = A[M][K] * BT[N][K]^T + bias ----------------
template <int MODE>
__global__ __launch_bounds__(256, 2)
void gemm_bt(const __bf16* __restrict__ A, const __bf16* __restrict__ BT,
             const float* __restrict__ b0, const float* __restrict__ b1,
             const float* __restrict__ b2,
             __bf16* __restrict__ Cb, float* __restrict__ Cf,
             int M, int N, int K) {
  __shared__ __bf16 As[128 * 32];
  __shared__ __bf16 Bs[128 * 32];
  const int t = threadIdx.x;
  const int lane = t & 63, w = t >> 6;
  const int lr = lane & 15, lg = lane >> 4;
  // XCD-aware block swizzle (grid size is a multiple of 8)
  const int gx = gridDim.x;
  const int flat = blockIdx.y * gx + blockIdx.x;
  const int cpx = (gx * gridDim.y) >> 3;
  const int sb = (flat & 7) * cpx + (flat >> 3);
  const int m0 = (sb / gx) * 128, n0 = (sb % gx) * 128;
  const int rm = (w >> 1) * 64, cn = (w & 1) * 64;
  const int srow = t >> 2, scol = (t & 3) * 8;

  const f32x4 fz = {0.f, 0.f, 0.f, 0.f};
  f32x4 acc[4][4];
#pragma unroll
  for (int mi = 0; mi < 4; mi++)
#pragma unroll
    for (int ni = 0; ni < 4; ni++) acc[mi][ni] = fz;

  for (int kt = 0; kt < K; kt += 32) {
    __syncthreads();
    lds_load16(A + (size_t)(m0 + srow) * K + kt + scol, As + w * 512);
    lds_load16(A + (size_t)(m0 + 64 + srow) * K + kt + scol, As + 2048 + w * 512);
    lds_load16(BT + (size_t)(n0 + srow) * K + kt + scol, Bs + w * 512);
    lds_load16(BT + (size_t)(n0 + 64 + srow) * K + kt + scol, Bs + 2048 + w * 512);
    __syncthreads();
    v8bf16 af[4], bfr[4];
#pragma unroll
    for (int i = 0; i < 4; i++)
      af[i] = *(const v8bf16*)&As[(rm + i * 16 + lr) * 32 + lg * 8];
#pragma unroll
    for (int i = 0; i < 4; i++)
      bfr[i] = *(const v8bf16*)&Bs[(cn + i * 16 + lr) * 32 + lg * 8];
#pragma unroll
    for (int mi = 0; mi < 4; mi++)
#pragma unroll
      for (int ni = 0; ni < 4; ni++)
        acc[mi][ni] = __builtin_amdgcn_mfma_f32_16x16x32_bf16(af[mi], bfr[ni], acc[mi][ni], 0, 0, 0);
  }

#pragma unroll
  for (int ni = 0; ni < 4; ni++) {
    int col = n0 + cn + ni * 16 + lr;
    float bias, scale = 1.0f;
    if (MODE == 0) {
      if (col < 2048)      { bias = b0[col];        scale = QSCALE; }
      else if (col < 2560) { bias = b1[col - 2048]; }
      else                 { bias = b2[col - 2560]; }
    } else {
      bias = b0[col];
    }
#pragma unroll
    for (int mi = 0; mi < 4; mi++)
#pragma unroll
      for (int r = 0; r < 4; r++) {
        int row = m0 + rm + mi * 16 + lg * 4 + r;
        float v = acc[mi][ni][r] + bias;
        if (MODE == 0) Cb[(size_t)row * N + col] = (__bf16)(v * scale);
        else           Cf[(size_t)row * N + col] = v;
      }
  }
}

// ---------------- GQA flash attention (8 waves, T15 double-pipeline) ----------------
// S^T = mfma(K,Q): lane holds 4 consecutive keys for fixed q -> packed P writes.
// Row-sum via MFMA with ones-vector. Per iter: QK^T(kt+1) overlaps softmax+PV(kt)
// (independent chains fill the P LDS-roundtrip and exp2 bubbles). 3 K/V buffers.
// QKV: [4096][3072] bf16 (Q pre-scaled by QSCALE incl. log2e, K at 2048, V at 2560)
// VT:  [512][4096] bf16  (VT[g*64+d][b*2048+s])
// ctx: [4096][2048] bf16 out
__global__ __launch_bounds__(512, 2)
void attn_kernel(const __bf16* __restrict__ QKV, const __bf16* __restrict__ VT,
                 __bf16* __restrict__ ctx) {
  // 68KB: 3 K/V buffers (each K:0..4095, V:4096..8191), P: per-wave [32][40] at 24576+w*1280
  __shared__ __bf16 smem[34816];
  const int t = threadIdx.x;
  const int lane = t & 63, w = t >> 6;
  const int lr = lane & 15, lg = lane >> 4;
  // XCD-aware swizzle: same head's q-tiles cluster on one XCD (grid 512 = 8*64)
  const int flat = blockIdx.y * 8 + blockIdx.x;
  const int swz = (flat & 7) * 64 + (flat >> 3);
  const int qt = swz & 7, bh = swz >> 3;
  const int b = bh >> 5, h = bh & 31, g = h >> 2;
  const int q0 = qt * 256;
  // pre-swizzled source column for staging (inverse of the XOR used on reads)
  const int scol = (((t & 7) ^ ((t >> 3) & 7)) << 3);

  // Q fragments straight from global (B-operand of swapped QK^T: lane lr = q col)
  v8bf16 qa[2][2];
#pragma unroll
  for (int mi = 0; mi < 2; mi++)
#pragma unroll
    for (int dk2 = 0; dk2 < 2; dk2++)
      qa[mi][dk2] = *(const v8bf16*)(QKV +
          (size_t)(b * S_LEN + q0 + w * 32 + mi * 16 + lr) * NQKV + h * DK + dk2 * 32 + lg * 8);

  // staging sources (thread t covers row t>>3, 8 cols at scol), advanced per stage
  const __bf16* kp = QKV + (size_t)(b * S_LEN + (t >> 3)) * NQKV + D_MODEL + g * DK + scol;
  const __bf16* vp = VT + (size_t)(g * DK + (t >> 3)) * NTOK + b * S_LEN + scol;

  auto stage = [&](__bf16* buf) {
    lds_load16(kp, buf + t * 8);
    lds_load16(vp, buf + 4096 + t * 8);
    kp += (size_t)64 * NQKV;
    vp += 64;
  };

  __bf16* bufA = smem;
  __bf16* bufB = smem + 8192;
  __bf16* bufC = smem + 16384;

  // prologue: tiles 0,1 in flight (4 outstanding vmem ops per wave)
  stage(bufA);
  stage(bufB);

  // loop-invariant swizzled lane offsets for K/V fragment reads (row = lr)
  const int kloff0 = lr * 64 + ((lg * 8) ^ ((lr & 7) << 3));
  const int kloff1 = lr * 64 + ((32 + lg * 8) ^ ((lr & 7) << 3));
  __bf16* Pw = smem + 24576 + w * 1280;  // [32][40]

  const __bf16 one1 = (__bf16)1.0f;
  const v8bf16 ones = { one1, one1, one1, one1, one1, one1, one1, one1 };
  const f32x4 fz = {0.f, 0.f, 0.f, 0.f};
  f32x4 o[2][4], o_sum[2];
  o_sum[0] = fz; o_sum[1] = fz;
#pragma unroll
  for (int mi = 0; mi < 2; mi++)
#pragma unroll
    for (int nd = 0; nd < 4; nd++) o[mi][nd] = fz;

  f32x4 stc[4][2], stn[4][2];

  // QK^T for one tile -> st[ni][mi][r] = S[q = w*32+mi*16+lr][key = ni*16+lg*4+r]
  auto qk = [&](const __bf16* Kb, f32x4 (&st)[4][2]) {
    const __bf16* k0 = Kb + kloff0;
    const __bf16* k1 = Kb + kloff1;
#pragma unroll
    for (int ni = 0; ni < 4; ni++) { st[ni][0] = fz; st[ni][1] = fz; }
    __builtin_amdgcn_s_setprio(1);
#pragma unroll
    for (int ni = 0; ni < 4; ni++) {
      v8bf16 kb = *(const v8bf16*)(k0 + ni * 1024);
      st[ni][0] = __builtin_amdgcn_mfma_f32_16x16x32_bf16(kb, qa[0][0], st[ni][0], 0, 0, 0);
      st[ni][1] = __builtin_amdgcn_mfma_f32_16x16x32_bf16(kb, qa[1][0], st[ni][1], 0, 0, 0);
    }
#pragma unroll
    for (int ni = 0; ni < 4; ni++) {
      v8bf16 kb = *(const v8bf16*)(k1 + ni * 1024);
      st[ni][0] = __builtin_amdgcn_mfma_f32_16x16x32_bf16(kb, qa[0][1], st[ni][0], 0, 0, 0);
      st[ni][1] = __builtin_amdgcn_mfma_f32_16x16x32_bf16(kb, qa[1][1], st[ni][1], 0, 0, 0);
    }
    __builtin_amdgcn_s_setprio(0);
  };

  // softmax + PV for one tile (consumes st, V of Kb)
  auto pv = [&](f32x4 (&st)[4][2], const __bf16* Kb) {
#pragma unroll
    for (int ks = 0; ks < 2; ks++) {
      const __bf16* vbase = Kb + 4096 + (ks ? kloff1 : kloff0);
#pragma unroll
      for (int mi = 0; mi < 2; mi++)
#pragma unroll
        for (int ni2 = 0; ni2 < 2; ni2++) {
          f32x4 sv = st[2 * ks + ni2][mi];
          bf16x4 pk = { (__bf16)exp2f(sv[0]), (__bf16)exp2f(sv[1]),
                        (__bf16)exp2f(sv[2]), (__bf16)exp2f(sv[3]) };
          *(bf16x4*)(Pw + (mi * 16 + lr) * 40 + ni2 * 16 + lg * 4) = pk;
        }
      v8bf16 pa0 = *(const v8bf16*)(Pw + lr * 40 + lg * 8);
      v8bf16 pa1 = *(const v8bf16*)(Pw + (16 + lr) * 40 + lg * 8);
      __builtin_amdgcn_s_setprio(1);
#pragma unroll
      for (int nd = 0; nd < 4; nd++) {
        v8bf16 vb = *(const v8bf16*)(vbase + nd * 1024);
        o[0][nd] = __builtin_amdgcn_mfma_f32_16x16x32_bf16(pa0, vb, o[0][nd], 0, 0, 0);
        o[1][nd] = __builtin_amdgcn_mfma_f32_16x16x32_bf16(pa1, vb, o[1][nd], 0, 0, 0);
      }
      o_sum[0] = __builtin_amdgcn_mfma_f32_16x16x32_bf16(pa0, ones, o_sum[0], 0, 0, 0);
      o_sum[1] = __builtin_amdgcn_mfma_f32_16x16x32_bf16(pa1, ones, o_sum[1], 0, 0, 0);
      __builtin_amdgcn_s_setprio(0);
    }
  };

  // prologue compute: scores for tile 0 (tile 0 landed after vmcnt(2))
  asm volatile("s_waitcnt vmcnt(2)" ::: "memory");
  __builtin_amdgcn_s_barrier();
  __builtin_amdgcn_sched_barrier(0);
  qk(bufA, stc);

  // main pipeline: iter kt does QK(kt+1) + softmax/PV(kt); stage(kt+2)
  __bf16* cur = bufA;
  __bf16* nxt = bufB;
  __bf16* fre = bufC;
  for (int kt = 0; kt < 31; kt++) {
    asm volatile("s_waitcnt vmcnt(0)" ::: "memory");  // tiles <= kt+1 landed (this wave)
    __builtin_amdgcn_s_barrier();                     // => landed for all waves; PV(kt-1) done by all
    __builtin_amdgcn_sched_barrier(0);
    if (kt < 30) stage(fre);  // tile kt+2 over buffer last read at kt-1 (WAR-safe post-barrier)
    qk(nxt, stn);             // independent of pv(kt) chain -> fills its bubbles
    pv(stc, cur);
#pragma unroll
    for (int ni = 0; ni < 4; ni++) { stc[ni][0] = stn[ni][0]; stc[ni][1] = stn[ni][1]; }
    __bf16* tmp = cur; cur = nxt; nxt = fre; fre = tmp;
  }
  // tail: tile 31 softmax + PV (V landed; staged at kt=29, drained at kt=30)
  pv(stc, cur);

  // epilogue: o_sum already lives in o-row layout (row = lg*4+r); no shuffles
#pragma unroll
  for (int mi = 0; mi < 2; mi++)
#pragma unroll
    for (int r = 0; r < 4; r++) {
      float inv = 1.0f / o_sum[mi][r];
      int row = b * S_LEN + q0 + w * 32 + mi * 16 + lg * 4 + r;
#pragma unroll
      for (int nd = 0; nd < 4; nd++)
        ctx[(size_t)row * D_MODEL + h * DK + nd * 16 + lr] = (__bf16)(o[mi][nd][r] * inv);
    }
}

extern "C" void kernel_launch(void* const* d_in, const int* in_sizes, int n_in,
                              void* d_out, int out_size, void* d_ws, size_t ws_size,
                              hipStream_t stream) {
  (void)in_sizes; (void)n_in; (void)out_size; (void)ws_size;
  const float* x  = (const float*)d_in[0];
  const float* wq = (const float*)d_in[1];
  const float* bq = (const float*)d_in[2];
  const float* wk = (const float*)d_in[3];
  const float* bk = (const float*)d_in[4];
  const float* wv = (const float*)d_in[5];
  const float* bv = (const float*)d_in[6];
  const float* wo = (const float*)d_in[7];
  const float* bo = (const float*)d_in[8];

  char* ws = (char*)d_ws;
  __bf16* xb    = (__bf16*)(ws);                 // [4096][2048]   16 MB
  __bf16* wqkvT = (__bf16*)(ws + 16777216);      // [3072][2048]   12 MB
  __bf16* woT   = (__bf16*)(ws + 29360128);      // [2048][2048]    8 MB
  __bf16* QKVb  = (__bf16*)(ws + 37748736);      // [4096][3072]   24 MB
  __bf16* VbT   = (__bf16*)(ws + 62914560);      // [512][4096]     4 MB
  __bf16* ctx   = (__bf16*)(ws + 67108864);      // [4096][2048]   16 MB

  dim3 tb(32, 8);
  cvt_f32_bf16<<<8192, 256, 0, stream>>>(x, xb, NTOK * D_MODEL);
  transpose_cvt<<<dim3(64, 64), tb, 0, stream>>>(wq, wqkvT, 2048, 2048);
  transpose_cvt<<<dim3(16, 64), tb, 0, stream>>>(wk, wqkvT + 2048 * 2048, 2048, 512);
  transpose_cvt<<<dim3(16, 64), tb, 0, stream>>>(wv, wqkvT + 2560 * 2048, 2048, 512);
  transpose_cvt<<<dim3(64, 64), tb, 0, stream>>>(wo, woT, 2048, 2048);

  gemm_bt<0><<<dim3(24, 32), 256, 0, stream>>>(xb, wqkvT, bq, bk, bv,
                                               QKVb, nullptr, NTOK, NQKV, 2048);
  transpose_bf16<<<dim3(16, 128), tb, 0, stream>>>(QKVb + 2560, VbT, 4096, 512, 3072, 4096);
  attn_kernel<<<dim3(8, 64), 512, 0, stream>>>(QKVb, VbT, ctx);
  gemm_bt<1><<<dim3(16, 32), 256, 0, stream>>>(ctx, woT, bo, nullptr, nullptr,
                                               nullptr, (float*)d_out, NTOK, 2048, 2048);
}

// Round 11
// 233.801 us; speedup vs baseline: 1.0766x; 1.0739x over previous
//
#include <hip/hip_runtime.h>
#include <hip/hip_bf16.h>

typedef __bf16 v8bf16 __attribute__((ext_vector_type(8)));
typedef __bf16 bf16x4 __attribute__((ext_vector_type(4)));
typedef float  f32x4  __attribute__((ext_vector_type(4)));

#define D_MODEL 2048
#define S_LEN   2048
#define NHEADS  32
#define NGROUPS 8
#define DK      64
#define NTOK    4096   // B*S
#define NQKV    3072   // 2048 + 512 + 512
// 0.125 (1/sqrt(64)) * log2(e): softmax done in base-2 domain
#define QSCALE  0.18033688011112042f

__device__ __forceinline__ void lds_load16(const void* g, void* l) {
  __builtin_amdgcn_global_load_lds(
      (__attribute__((address_space(1))) unsigned int*)g,
      (__attribute__((address_space(3))) unsigned int*)l, 16, 0, 0);
}

// ---------------- fp32 -> bf16 elementwise ----------------
__global__ __launch_bounds__(256)
void cvt_f32_bf16(const float* __restrict__ in, __bf16* __restrict__ out, int n) {
  int i = (blockIdx.x * 256 + threadIdx.x) * 4;
  if (i >= n) return;
  float4 v = *(const float4*)(in + i);
  bf16x4 o = { (__bf16)v.x, (__bf16)v.y, (__bf16)v.z, (__bf16)v.w };
  *(bf16x4*)(out + i) = o;
}

// ---------------- fp32 [R][C] -> bf16 [C][R] transpose-convert ----------------
__global__ __launch_bounds__(256)
void transpose_cvt(const float* __restrict__ in, __bf16* __restrict__ out, int R, int C) {
  __shared__ float tile[32][33];
  int tx = threadIdx.x, ty = threadIdx.y;
  int c0 = blockIdx.x * 32, r0 = blockIdx.y * 32;
#pragma unroll
  for (int j = 0; j < 4; j++)
    tile[ty + 8 * j][tx] = in[(size_t)(r0 + ty + 8 * j) * C + c0 + tx];
  __syncthreads();
#pragma unroll
  for (int j = 0; j < 4; j++)
    out[(size_t)(c0 + ty + 8 * j) * R + r0 + tx] = (__bf16)tile[tx][ty + 8 * j];
}

// ---------------- bf16 [R][Csub] (ld=ldin) -> bf16 [Csub][R] (ld=ldout) ----------------
__global__ __launch_bounds__(256)
void transpose_bf16(const __bf16* __restrict__ in, __bf16* __restrict__ out,
                    int R, int C, int ldin, int ldout) {
  __shared__ __bf16 tile[32][33];
  int tx = threadIdx.x, ty = threadIdx.y;
  int c0 = blockIdx.x * 32, r0 = blockIdx.y * 32;
#pragma unroll
  for (int j = 0; j < 4; j++)
    tile[ty + 8 * j][tx] = in[(size_t)(r0 + ty + 8 * j) * ldin + c0 + tx];
  __syncthreads();
#pragma unroll
  for (int j = 0; j < 4; j++)
    out[(size_t)(c0 + ty + 8 * j) * ldout + r0 + tx] = tile[tx][ty + 8 * j];
}

// ---------------- GEMM: C[M][N] = A[M][K] * BT[N][K]^T + bias ----------------
template <int MODE>
__global__ __launch_bounds__(256, 2)
void gemm_bt(const __bf16* __restrict__ A, const __bf16* __restrict__ BT,
             const float* __restrict__ b0, const float* __restrict__ b1,
             const float* __restrict__ b2,
             __bf16* __restrict__ Cb, float* __restrict__ Cf,
             int M, int N, int K) {
  __shared__ __bf16 As[128 * 32];
  __shared__ __bf16 Bs[128 * 32];
  const int t = threadIdx.x;
  const int lane = t & 63, w = t >> 6;
  const int lr = lane & 15, lg = lane >> 4;
  // XCD-aware block swizzle (grid size is a multiple of 8)
  const int gx = gridDim.x;
  const int flat = blockIdx.y * gx + blockIdx.x;
  const int cpx = (gx * gridDim.y) >> 3;
  const int sb = (flat & 7) * cpx + (flat >> 3);
  const int m0 = (sb / gx) * 128, n0 = (sb % gx) * 128;
  const int rm = (w >> 1) * 64, cn = (w & 1) * 64;
  const int srow = t >> 2, scol = (t & 3) * 8;

  const f32x4 fz = {0.f, 0.f, 0.f, 0.f};
  f32x4 acc[4][4];
#pragma unroll
  for (int mi = 0; mi < 4; mi++)
#pragma unroll
    for (int ni = 0; ni < 4; ni++) acc[mi][ni] = fz;

  for (int kt = 0; kt < K; kt += 32) {
    __syncthreads();
    lds_load16(A + (size_t)(m0 + srow) * K + kt + scol, As + w * 512);
    lds_load16(A + (size_t)(m0 + 64 + srow) * K + kt + scol, As + 2048 + w * 512);
    lds_load16(BT + (size_t)(n0 + srow) * K + kt + scol, Bs + w * 512);
    lds_load16(BT + (size_t)(n0 + 64 + srow) * K + kt + scol, Bs + 2048 + w * 512);
    __syncthreads();
    v8bf16 af[4], bfr[4];
#pragma unroll
    for (int i = 0; i < 4; i++)
      af[i] = *(const v8bf16*)&As[(rm + i * 16 + lr) * 32 + lg * 8];
#pragma unroll
    for (int i = 0; i < 4; i++)
      bfr[i] = *(const v8bf16*)&Bs[(cn + i * 16 + lr) * 32 + lg * 8];
#pragma unroll
    for (int mi = 0; mi < 4; mi++)
#pragma unroll
      for (int ni = 0; ni < 4; ni++)
        acc[mi][ni] = __builtin_amdgcn_mfma_f32_16x16x32_bf16(af[mi], bfr[ni], acc[mi][ni], 0, 0, 0);
  }

#pragma unroll
  for (int ni = 0; ni < 4; ni++) {
    int col = n0 + cn + ni * 16 + lr;
    float bias, scale = 1.0f;
    if (MODE == 0) {
      if (col < 2048)      { bias = b0[col];        scale = QSCALE; }
      else if (col < 2560) { bias = b1[col - 2048]; }
      else                 { bias = b2[col - 2560]; }
    } else {
      bias = b0[col];
    }
#pragma unroll
    for (int mi = 0; mi < 4; mi++)
#pragma unroll
      for (int r = 0; r < 4; r++) {
        int row = m0 + rm + mi * 16 + lg * 4 + r;
        float v = acc[mi][ni][r] + bias;
        if (MODE == 0) Cb[(size_t)row * N + col] = (__bf16)(v * scale);
        else           Cf[(size_t)row * N + col] = v;
      }
  }
}

// ---------------- GQA flash attention (8 waves x 16 q, occupancy-optimized) ----------------
// S^T = mfma(K,Q): lane holds 4 consecutive keys for fixed q -> packed P writes.
// Row-sum via ones-MFMA. QBLK=128 (16 q/wave) doubles the grid to 1024 blocks ->
// 3 blocks/CU resident (24 waves/CU, +50% vs QBLK=256) for latency hiding.
// QKV: [4096][3072] bf16 (Q pre-scaled by QSCALE incl. log2e, K at 2048, V at 2560)
// VT:  [512][4096] bf16  (VT[g*64+d][b*2048+s])
// ctx: [4096][2048] bf16 out
__global__ __launch_bounds__(512, 6)
void attn_kernel(const __bf16* __restrict__ QKV, const __bf16* __restrict__ VT,
                 __bf16* __restrict__ ctx) {
  // 42KB: buf0 {K:0..4095, V:4096..8191}, buf1 {8192..16383},
  // P: per-wave [16 q][40 keys] at 16384 + w*640
  __shared__ __bf16 smem[21504];
  const int t = threadIdx.x;
  const int lane = t & 63, w = t >> 6;
  const int lr = lane & 15, lg = lane >> 4;
  // XCD-aware swizzle (grid 1024 = 8 XCD chunks of 128 = 8 heads x 16 q-tiles)
  const int flat = blockIdx.y * 16 + blockIdx.x;
  const int swz = (flat & 7) * 128 + (flat >> 3);
  const int qt = swz & 15, bh = swz >> 4;
  const int b = bh >> 5, h = bh & 31, g = h >> 2;
  const int q0 = qt * 128;
  // pre-swizzled source column for staging (inverse of the XOR used on reads)
  const int scol = (((t & 7) ^ ((t >> 3) & 7)) << 3);

  // Q fragments straight from global (B-operand of swapped QK^T: lane lr = q col)
  v8bf16 qa[2];
#pragma unroll
  for (int dk2 = 0; dk2 < 2; dk2++)
    qa[dk2] = *(const v8bf16*)(QKV +
        (size_t)(b * S_LEN + q0 + w * 16 + lr) * NQKV + h * DK + dk2 * 32 + lg * 8);

  // staging sources (thread t covers row t>>3, 8 cols at scol), increment-only
  const __bf16* kp = QKV + (size_t)(b * S_LEN + (t >> 3)) * NQKV + D_MODEL + g * DK + scol;
  const __bf16* vp = VT + (size_t)(g * DK + (t >> 3)) * NTOK + b * S_LEN + scol;

  // prologue: stage tile 0 into buf0 (one K + one V load16 per thread)
  lds_load16(kp, smem + t * 8);
  lds_load16(vp, smem + 4096 + t * 8);
  __syncthreads();

  // loop-invariant swizzled lane offsets for K/V fragment reads (row = lr)
  const int kloff0 = lr * 64 + ((lg * 8) ^ ((lr & 7) << 3));
  const int kloff1 = lr * 64 + ((32 + lg * 8) ^ ((lr & 7) << 3));
  __bf16* Pw = smem + 16384 + w * 640;  // [16][40]

  const __bf16 one1 = (__bf16)1.0f;
  const v8bf16 ones = { one1, one1, one1, one1, one1, one1, one1, one1 };
  const f32x4 fz = {0.f, 0.f, 0.f, 0.f};
  f32x4 o[4], o_sum;
  o_sum = fz;
#pragma unroll
  for (int nd = 0; nd < 4; nd++) o[nd] = fz;

#pragma unroll 2
  for (int kt = 0; kt < 32; kt++) {
    // prefetch next K/V tile into the other buffer
    if (kt < 31) {
      __bf16* nb = smem + ((kt & 1) ^ 1) * 8192;
      lds_load16(kp + (size_t)64 * NQKV, nb + t * 8);
      lds_load16(vp + 64, nb + 4096 + t * 8);
      kp += (size_t)64 * NQKV;
      vp += 64;
    }
    const __bf16* Kb = smem + (kt & 1) * 8192;
    const __bf16* k0 = Kb + kloff0;
    const __bf16* k1 = Kb + kloff1;

    // S^T = K Q^T: st[ni][r] = S[q = w*16+lr][key = ni*16+lg*4+r]
    f32x4 st[4];
#pragma unroll
    for (int ni = 0; ni < 4; ni++) st[ni] = fz;
    __builtin_amdgcn_s_setprio(1);
#pragma unroll
    for (int ni = 0; ni < 4; ni++) {
      v8bf16 kb = *(const v8bf16*)(k0 + ni * 1024);
      st[ni] = __builtin_amdgcn_mfma_f32_16x16x32_bf16(kb, qa[0], st[ni], 0, 0, 0);
    }
#pragma unroll
    for (int ni = 0; ni < 4; ni++) {
      v8bf16 kb = *(const v8bf16*)(k1 + ni * 1024);
      st[ni] = __builtin_amdgcn_mfma_f32_16x16x32_bf16(kb, qa[1], st[ni], 0, 0, 0);
    }
    __builtin_amdgcn_s_setprio(0);

    // per 32-key half: packed P writes, 1 b128 read-back, 4 V reads, PV + ones-MFMA row-sum
#pragma unroll
    for (int ks = 0; ks < 2; ks++) {
      const __bf16* vbase = (ks ? k1 : k0) + 4096;
#pragma unroll
      for (int ni2 = 0; ni2 < 2; ni2++) {
        f32x4 sv = st[2 * ks + ni2];
        bf16x4 pk = { (__bf16)exp2f(sv[0]), (__bf16)exp2f(sv[1]),
                      (__bf16)exp2f(sv[2]), (__bf16)exp2f(sv[3]) };
        *(bf16x4*)(Pw + lr * 40 + ni2 * 16 + lg * 4) = pk;
      }
      v8bf16 pa = *(const v8bf16*)(Pw + lr * 40 + lg * 8);
      __builtin_amdgcn_s_setprio(1);
#pragma unroll
      for (int nd = 0; nd < 4; nd++) {
        v8bf16 vb = *(const v8bf16*)(vbase + nd * 1024);
        o[nd] = __builtin_amdgcn_mfma_f32_16x16x32_bf16(pa, vb, o[nd], 0, 0, 0);
      }
      o_sum = __builtin_amdgcn_mfma_f32_16x16x32_bf16(pa, ones, o_sum, 0, 0, 0);
      __builtin_amdgcn_s_setprio(0);
    }

    __syncthreads();  // drains prefetch vmcnt + protects buffer swap
  }

  // epilogue: o_sum already lives in o-row layout (row = lg*4+r); no shuffles
#pragma unroll
  for (int r = 0; r < 4; r++) {
    float inv = 1.0f / o_sum[r];
    int row = b * S_LEN + q0 + w * 16 + lg * 4 + r;
#pragma unroll
    for (int nd = 0; nd < 4; nd++)
      ctx[(size_t)row * D_MODEL + h * DK + nd * 16 + lr] = (__bf16)(o[nd][r] * inv);
  }
}

extern "C" void kernel_launch(void* const* d_in, const int* in_sizes, int n_in,
                              void* d_out, int out_size, void* d_ws, size_t ws_size,
                              hipStream_t stream) {
  (void)in_sizes; (void)n_in; (void)out_size; (void)ws_size;
  const float* x  = (const float*)d_in[0];
  const float* wq = (const float*)d_in[1];
  const float* bq = (const float*)d_in[2];
  const float* wk = (const float*)d_in[3];
  const float* bk = (const float*)d_in[4];
  const float* wv = (const float*)d_in[5];
  const float* bv = (const float*)d_in[6];
  const float* wo = (const float*)d_in[7];
  const float* bo = (const float*)d_in[8];

  char* ws = (char*)d_ws;
  __bf16* xb    = (__bf16*)(ws);                 // [4096][2048]   16 MB
  __bf16* wqkvT = (__bf16*)(ws + 16777216);      // [3072][2048]   12 MB
  __bf16* woT   = (__bf16*)(ws + 29360128);      // [2048][2048]    8 MB
  __bf16* QKVb  = (__bf16*)(ws + 37748736);      // [4096][3072]   24 MB
  __bf16* VbT   = (__bf16*)(ws + 62914560);      // [512][4096]     4 MB
  __bf16* ctx   = (__bf16*)(ws + 67108864);      // [4096][2048]   16 MB

  dim3 tb(32, 8);
  cvt_f32_bf16<<<8192, 256, 0, stream>>>(x, xb, NTOK * D_MODEL);
  transpose_cvt<<<dim3(64, 64), tb, 0, stream>>>(wq, wqkvT, 2048, 2048);
  transpose_cvt<<<dim3(16, 64), tb, 0, stream>>>(wk, wqkvT + 2048 * 2048, 2048, 512);
  transpose_cvt<<<dim3(16, 64), tb, 0, stream>>>(wv, wqkvT + 2560 * 2048, 2048, 512);
  transpose_cvt<<<dim3(64, 64), tb, 0, stream>>>(wo, woT, 2048, 2048);

  gemm_bt<0><<<dim3(24, 32), 256, 0, stream>>>(xb, wqkvT, bq, bk, bv,
                                               QKVb, nullptr, NTOK, NQKV, 2048);
  transpose_bf16<<<dim3(16, 128), tb, 0, stream>>>(QKVb + 2560, VbT, 4096, 512, 3072, 4096);
  attn_kernel<<<dim3(16, 64), 512, 0, stream>>>(QKVb, VbT, ctx);
  gemm_bt<1><<<dim3(16, 32), 256, 0, stream>>>(ctx, woT, bo, nullptr, nullptr,
                                               nullptr, (float*)d_out, NTOK, 2048, 2048);
}

// Round 12
// 231.063 us; speedup vs baseline: 1.0894x; 1.0118x over previous
//
#include <hip/hip_runtime.h>
#include <hip/hip_bf16.h>

typedef __bf16 v8bf16 __attribute__((ext_vector_type(8)));
typedef __bf16 bf16x4 __attribute__((ext_vector_type(4)));
typedef float  f32x4  __attribute__((ext_vector_type(4)));

#define D_MODEL 2048
#define S_LEN   2048
#define NHEADS  32
#define NGROUPS 8
#define DK      64
#define NTOK    4096   // B*S
#define NQKV    3072   // 2048 + 512 + 512
// 0.125 (1/sqrt(64)) * log2(e): softmax done in base-2 domain
#define QSCALE  0.18033688011112042f

__device__ __forceinline__ void lds_load16(const void* g, void* l) {
  __builtin_amdgcn_global_load_lds(
      (__attribute__((address_space(1))) unsigned int*)g,
      (__attribute__((address_space(3))) unsigned int*)l, 16, 0, 0);
}

// XOR swizzle for [*][64] bf16 tiles (128B row stride): col ^= (row&7)<<3
__device__ __forceinline__ int sw64(int row, int col) {
  return row * 64 + (col ^ ((row & 7) << 3));
}

// ---------------- fp32 -> bf16 elementwise ----------------
__global__ __launch_bounds__(256)
void cvt_f32_bf16(const float* __restrict__ in, __bf16* __restrict__ out, int n) {
  int i = (blockIdx.x * 256 + threadIdx.x) * 4;
  if (i >= n) return;
  float4 v = *(const float4*)(in + i);
  bf16x4 o = { (__bf16)v.x, (__bf16)v.y, (__bf16)v.z, (__bf16)v.w };
  *(bf16x4*)(out + i) = o;
}

// ---------------- fp32 [R][C] -> bf16 [C][R] transpose-convert ----------------
__global__ __launch_bounds__(256)
void transpose_cvt(const float* __restrict__ in, __bf16* __restrict__ out, int R, int C) {
  __shared__ float tile[32][33];
  int tx = threadIdx.x, ty = threadIdx.y;
  int c0 = blockIdx.x * 32, r0 = blockIdx.y * 32;
#pragma unroll
  for (int j = 0; j < 4; j++)
    tile[ty + 8 * j][tx] = in[(size_t)(r0 + ty + 8 * j) * C + c0 + tx];
  __syncthreads();
#pragma unroll
  for (int j = 0; j < 4; j++)
    out[(size_t)(c0 + ty + 8 * j) * R + r0 + tx] = (__bf16)tile[tx][ty + 8 * j];
}

// ---------------- bf16 [R][Csub] (ld=ldin) -> bf16 [Csub][R] (ld=ldout) ----------------
__global__ __launch_bounds__(256)
void transpose_bf16(const __bf16* __restrict__ in, __bf16* __restrict__ out,
                    int R, int C, int ldin, int ldout) {
  __shared__ __bf16 tile[32][33];
  int tx = threadIdx.x, ty = threadIdx.y;
  int c0 = blockIdx.x * 32, r0 = blockIdx.y * 32;
#pragma unroll
  for (int j = 0; j < 4; j++)
    tile[ty + 8 * j][tx] = in[(size_t)(r0 + ty + 8 * j) * ldin + c0 + tx];
  __syncthreads();
#pragma unroll
  for (int j = 0; j < 4; j++)
    out[(size_t)(c0 + ty + 8 * j) * ldout + r0 + tx] = tile[tx][ty + 8 * j];
}

// ---------------- big-tile GEMM: C[M][N] = A[M][K] * BT[N][K]^T + bias ----------------
// BM=256, BN=192 (MODE 0, QKV) or 128 (MODE 1, WO), BK=64, 8 waves (2M x 4N).
// sw64-swizzled LDS (conflict-free b128 frag reads, sources pre-swizzled),
// counted-vmcnt 2-buffer pipeline (no vmcnt(0) drain in loop), XCD swizzle.
template <int MODE, int BN>
__global__ __launch_bounds__(512, 1)
void gemm_big(const __bf16* __restrict__ A, const __bf16* __restrict__ BT,
              const float* __restrict__ b0, const float* __restrict__ b1,
              const float* __restrict__ b2,
              __bf16* __restrict__ Cb, float* __restrict__ Cf,
              int M, int N, int K) {
  constexpr int FN = BN / 64;        // B col-frags per wave (3 or 2); also B stage loads
  __shared__ __bf16 Alds[2 * 256 * 64];
  __shared__ __bf16 Blds[2 * BN * 64];
  const int t = threadIdx.x;
  const int lane = t & 63, w = t >> 6;
  const int lr = lane & 15, lg = lane >> 4;
  const int wm = w >> 2, wn = w & 3;
  // XCD-aware swizzle over a 1D grid (multiple of 8): consecutive swz share the A panel
  const int cpx = gridDim.x >> 3;
  const int swz = (blockIdx.x & 7) * cpx + (blockIdx.x >> 3);
  const int nbx = N / BN;
  const int m0 = (swz / nbx) * 256, n0 = (swz % nbx) * BN;
  // pre-swizzled source column for staging (inverse of sw64 on the read side)
  const int scol = (((t & 7) ^ ((t >> 3) & 7)) << 3);

  const __bf16* ap = A + (size_t)(m0 + (t >> 3)) * K + scol;
  const __bf16* bp = BT + (size_t)(n0 + (t >> 3)) * K + scol;

  auto stage = [&](int buf) {
    __bf16* ad = Alds + buf * 16384 + t * 8;
    __bf16* bd = Blds + buf * BN * 64 + t * 8;
#pragma unroll
    for (int i = 0; i < 4; i++) lds_load16(ap + (size_t)i * 64 * K, ad + i * 4096);
#pragma unroll
    for (int i = 0; i < FN; i++) lds_load16(bp + (size_t)i * 64 * K, bd + i * 4096);
    ap += 64; bp += 64;
  };

  const f32x4 fz = {0.f, 0.f, 0.f, 0.f};
  f32x4 acc[8][FN];
#pragma unroll
  for (int fm = 0; fm < 8; fm++)
#pragma unroll
    for (int fn = 0; fn < FN; fn++) acc[fm][fn] = fz;

  auto compute = [&](int buf) {
    const __bf16* Ab = Alds + buf * 16384;
    const __bf16* Bb = Blds + buf * BN * 64;
#pragma unroll
    for (int ks = 0; ks < 2; ks++) {
      v8bf16 bfr[FN];
#pragma unroll
      for (int fn = 0; fn < FN; fn++)
        bfr[fn] = *(const v8bf16*)&Bb[sw64(wn * (BN / 4) + fn * 16 + lr, ks * 32 + lg * 8)];
      __builtin_amdgcn_s_setprio(1);
#pragma unroll
      for (int fm = 0; fm < 8; fm++) {
        v8bf16 af = *(const v8bf16*)&Ab[sw64(wm * 128 + fm * 16 + lr, ks * 32 + lg * 8)];
#pragma unroll
        for (int fn = 0; fn < FN; fn++)
          acc[fm][fn] = __builtin_amdgcn_mfma_f32_16x16x32_bf16(af, bfr[fn], acc[fm][fn], 0, 0, 0);
      }
      __builtin_amdgcn_s_setprio(0);
    }
  };

  // prologue: tiles 0,1 in flight (2*(4+FN) outstanding per wave)
  stage(0);
  stage(1);
  for (int kt = 0; kt < 32; kt++) {
    if (kt < 31) {
      // wait tile kt landed; tile kt+1's 4+FN loads stay in flight
      if constexpr (FN == 3) asm volatile("s_waitcnt vmcnt(7)" ::: "memory");
      else                   asm volatile("s_waitcnt vmcnt(6)" ::: "memory");
    } else {
      asm volatile("s_waitcnt vmcnt(0)" ::: "memory");
    }
    __builtin_amdgcn_s_barrier();
    __builtin_amdgcn_sched_barrier(0);
    compute(kt & 1);
    if (kt < 30) {
      __builtin_amdgcn_sched_barrier(0);
      __builtin_amdgcn_s_barrier();   // all waves done reading buf (kt&1)
      __builtin_amdgcn_sched_barrier(0);
      stage(kt & 1);                  // tile kt+2 overwrites it
    }
  }

#pragma unroll
  for (int fn = 0; fn < FN; fn++) {
    int col = n0 + wn * (BN / 4) + fn * 16 + lr;
    float bias, scale = 1.0f;
    if (MODE == 0) {
      if (col < 2048)      { bias = b0[col];        scale = QSCALE; }
      else if (col < 2560) { bias = b1[col - 2048]; }
      else                 { bias = b2[col - 2560]; }
    } else {
      bias = b0[col];
    }
#pragma unroll
    for (int fm = 0; fm < 8; fm++)
#pragma unroll
      for (int r = 0; r < 4; r++) {
        int row = m0 + wm * 128 + fm * 16 + lg * 4 + r;
        float v = acc[fm][fn][r] + bias;
        if (MODE == 0) Cb[(size_t)row * N + col] = (__bf16)(v * scale);
        else           Cf[(size_t)row * N + col] = v;
      }
  }
}

// ---------------- GQA flash attention (8 waves x 32 q, r7 best-measured) ----------------
// S^T = mfma(K,Q): lane holds 4 consecutive keys for fixed q -> packed P writes.
// Row-sum via MFMA with ones-vector (matrix pipe, not VALU).
__global__ __launch_bounds__(512, 2)
void attn_kernel(const __bf16* __restrict__ QKV, const __bf16* __restrict__ VT,
                 __bf16* __restrict__ ctx) {
  // 52KB: buf0 {K:0..4095, V:4096..8191}, buf1 {8192..16383},
  // P: per-wave [32 q][40 keys] at 16384 + w*1280
  __shared__ __bf16 smem[26624];
  const int t = threadIdx.x;
  const int lane = t & 63, w = t >> 6;
  const int lr = lane & 15, lg = lane >> 4;
  // XCD-aware swizzle: same head's q-tiles cluster on one XCD (grid 512 = 8*64)
  const int flat = blockIdx.y * 8 + blockIdx.x;
  const int swz = (flat & 7) * 64 + (flat >> 3);
  const int qt = swz & 7, bh = swz >> 3;
  const int b = bh >> 5, h = bh & 31, g = h >> 2;
  const int q0 = qt * 256;
  const int scol = (((t & 7) ^ ((t >> 3) & 7)) << 3);

  v8bf16 qa[2][2];
#pragma unroll
  for (int mi = 0; mi < 2; mi++)
#pragma unroll
    for (int dk2 = 0; dk2 < 2; dk2++)
      qa[mi][dk2] = *(const v8bf16*)(QKV +
          (size_t)(b * S_LEN + q0 + w * 32 + mi * 16 + lr) * NQKV + h * DK + dk2 * 32 + lg * 8);

  const __bf16* kp = QKV + (size_t)(b * S_LEN + (t >> 3)) * NQKV + D_MODEL + g * DK + scol;
  const __bf16* vp = VT + (size_t)(g * DK + (t >> 3)) * NTOK + b * S_LEN + scol;

  lds_load16(kp, smem + t * 8);
  lds_load16(vp, smem + 4096 + t * 8);
  __syncthreads();

  const int kloff0 = lr * 64 + ((lg * 8) ^ ((lr & 7) << 3));
  const int kloff1 = lr * 64 + ((32 + lg * 8) ^ ((lr & 7) << 3));
  __bf16* Pw = smem + 16384 + w * 1280;  // [32][40]

  const __bf16 one1 = (__bf16)1.0f;
  const v8bf16 ones = { one1, one1, one1, one1, one1, one1, one1, one1 };
  const f32x4 fz = {0.f, 0.f, 0.f, 0.f};
  f32x4 o[2][4], o_sum[2];
  o_sum[0] = fz; o_sum[1] = fz;
#pragma unroll
  for (int mi = 0; mi < 2; mi++)
#pragma unroll
    for (int nd = 0; nd < 4; nd++) o[mi][nd] = fz;

#pragma unroll 2
  for (int kt = 0; kt < 32; kt++) {
    if (kt < 31) {
      __bf16* nb = smem + ((kt & 1) ^ 1) * 8192;
      lds_load16(kp + (size_t)64 * NQKV, nb + t * 8);
      lds_load16(vp + 64, nb + 4096 + t * 8);
      kp += (size_t)64 * NQKV;
      vp += 64;
    }
    const __bf16* Kb = smem + (kt & 1) * 8192;
    const __bf16* k0 = Kb + kloff0;
    const __bf16* k1 = Kb + kloff1;

    f32x4 st[4][2];
#pragma unroll
    for (int ni = 0; ni < 4; ni++) { st[ni][0] = fz; st[ni][1] = fz; }
    __builtin_amdgcn_s_setprio(1);
#pragma unroll
    for (int ni = 0; ni < 4; ni++) {
      v8bf16 kb = *(const v8bf16*)(k0 + ni * 1024);
      st[ni][0] = __builtin_amdgcn_mfma_f32_16x16x32_bf16(kb, qa[0][0], st[ni][0], 0, 0, 0);
      st[ni][1] = __builtin_amdgcn_mfma_f32_16x16x32_bf16(kb, qa[1][0], st[ni][1], 0, 0, 0);
    }
#pragma unroll
    for (int ni = 0; ni < 4; ni++) {
      v8bf16 kb = *(const v8bf16*)(k1 + ni * 1024);
      st[ni][0] = __builtin_amdgcn_mfma_f32_16x16x32_bf16(kb, qa[0][1], st[ni][0], 0, 0, 0);
      st[ni][1] = __builtin_amdgcn_mfma_f32_16x16x32_bf16(kb, qa[1][1], st[ni][1], 0, 0, 0);
    }
    __builtin_amdgcn_s_setprio(0);

#pragma unroll
    for (int ks = 0; ks < 2; ks++) {
      const __bf16* vbase = (ks ? k1 : k0) + 4096;
#pragma unroll
      for (int mi = 0; mi < 2; mi++)
#pragma unroll
        for (int ni2 = 0; ni2 < 2; ni2++) {
          f32x4 sv = st[2 * ks + ni2][mi];
          bf16x4 pk = { (__bf16)exp2f(sv[0]), (__bf16)exp2f(sv[1]),
                        (__bf16)exp2f(sv[2]), (__bf16)exp2f(sv[3]) };
          *(bf16x4*)(Pw + (mi * 16 + lr) * 40 + ni2 * 16 + lg * 4) = pk;
        }
      v8bf16 pa0 = *(const v8bf16*)(Pw + lr * 40 + lg * 8);
      v8bf16 pa1 = *(const v8bf16*)(Pw + (16 + lr) * 40 + lg * 8);
      __builtin_amdgcn_s_setprio(1);
#pragma unroll
      for (int nd = 0; nd < 4; nd++) {
        v8bf16 vb = *(const v8bf16*)(vbase + nd * 1024);
        o[0][nd] = __builtin_amdgcn_mfma_f32_16x16x32_bf16(pa0, vb, o[0][nd], 0, 0, 0);
        o[1][nd] = __builtin_amdgcn_mfma_f32_16x16x32_bf16(pa1, vb, o[1][nd], 0, 0, 0);
      }
      o_sum[0] = __builtin_amdgcn_mfma_f32_16x16x32_bf16(pa0, ones, o_sum[0], 0, 0, 0);
      o_sum[1] = __builtin_amdgcn_mfma_f32_16x16x32_bf16(pa1, ones, o_sum[1], 0, 0, 0);
      __builtin_amdgcn_s_setprio(0);
    }

    __syncthreads();
  }

#pragma unroll
  for (int mi = 0; mi < 2; mi++)
#pragma unroll
    for (int r = 0; r < 4; r++) {
      float inv = 1.0f / o_sum[mi][r];
      int row = b * S_LEN + q0 + w * 32 + mi * 16 + lg * 4 + r;
#pragma unroll
      for (int nd = 0; nd < 4; nd++)
        ctx[(size_t)row * D_MODEL + h * DK + nd * 16 + lr] = (__bf16)(o[mi][nd][r] * inv);
    }
}

extern "C" void kernel_launch(void* const* d_in, const int* in_sizes, int n_in,
                              void* d_out, int out_size, void* d_ws, size_t ws_size,
                              hipStream_t stream) {
  (void)in_sizes; (void)n_in; (void)out_size; (void)ws_size;
  const float* x  = (const float*)d_in[0];
  const float* wq = (const float*)d_in[1];
  const float* bq = (const float*)d_in[2];
  const float* wk = (const float*)d_in[3];
  const float* bk = (const float*)d_in[4];
  const float* wv = (const float*)d_in[5];
  const float* bv = (const float*)d_in[6];
  const float* wo = (const float*)d_in[7];
  const float* bo = (const float*)d_in[8];

  char* ws = (char*)d_ws;
  __bf16* xb    = (__bf16*)(ws);                 // [4096][2048]   16 MB
  __bf16* wqkvT = (__bf16*)(ws + 16777216);      // [3072][2048]   12 MB
  __bf16* woT   = (__bf16*)(ws + 29360128);      // [2048][2048]    8 MB
  __bf16* QKVb  = (__bf16*)(ws + 37748736);      // [4096][3072]   24 MB
  __bf16* VbT   = (__bf16*)(ws + 62914560);      // [512][4096]     4 MB
  __bf16* ctx   = (__bf16*)(ws + 67108864);      // [4096][2048]   16 MB

  dim3 tb(32, 8);
  cvt_f32_bf16<<<8192, 256, 0, stream>>>(x, xb, NTOK * D_MODEL);
  transpose_cvt<<<dim3(64, 64), tb, 0, stream>>>(wq, wqkvT, 2048, 2048);
  transpose_cvt<<<dim3(16, 64), tb, 0, stream>>>(wk, wqkvT + 2048 * 2048, 2048, 512);
  transpose_cvt<<<dim3(16, 64), tb, 0, stream>>>(wv, wqkvT + 2560 * 2048, 2048, 512);
  transpose_cvt<<<dim3(64, 64), tb, 0, stream>>>(wo, woT, 2048, 2048);

  gemm_big<0, 192><<<dim3(256), 512, 0, stream>>>(xb, wqkvT, bq, bk, bv,
                                                  QKVb, nullptr, NTOK, NQKV, 2048);
  transpose_bf16<<<dim3(16, 128), tb, 0, stream>>>(QKVb + 2560, VbT, 4096, 512, 3072, 4096);
  attn_kernel<<<dim3(8, 64), 512, 0, stream>>>(QKVb, VbT, ctx);
  gemm_big<1, 128><<<dim3(256), 512, 0, stream>>>(ctx, woT, bo, nullptr, nullptr,
                                                  nullptr, (float*)d_out, NTOK, 2048, 2048);
}

// Round 13
// 223.198 us; speedup vs baseline: 1.1278x; 1.0352x over previous
//
#include <hip/hip_runtime.h>
#include <hip/hip_bf16.h>

typedef __bf16 v8bf16 __attribute__((ext_vector_type(8)));
typedef __bf16 bf16x4 __attribute__((ext_vector_type(4)));
typedef float  f32x4  __attribute__((ext_vector_type(4)));

#define D_MODEL 2048
#define S_LEN   2048
#define NHEADS  32
#define NGROUPS 8
#define DK      64
#define NTOK    4096   // B*S
#define NQKV    3072   // 2048 + 512 + 512
// 0.125 (1/sqrt(64)) * log2(e): softmax done in base-2 domain
#define QSCALE  0.18033688011112042f

__device__ __forceinline__ void lds_load16(const void* g, void* l) {
  __builtin_amdgcn_global_load_lds(
      (__attribute__((address_space(1))) unsigned int*)g,
      (__attribute__((address_space(3))) unsigned int*)l, 16, 0, 0);
}

// XOR swizzle for [*][64] bf16 tiles (128B row stride): col ^= (row&7)<<3
__device__ __forceinline__ int sw64(int row, int col) {
  return row * 64 + (col ^ ((row & 7) << 3));
}

// ---------------- fp32 -> bf16 elementwise ----------------
__global__ __launch_bounds__(256)
void cvt_f32_bf16(const float* __restrict__ in, __bf16* __restrict__ out, int n) {
  int i = (blockIdx.x * 256 + threadIdx.x) * 4;
  if (i >= n) return;
  float4 v = *(const float4*)(in + i);
  bf16x4 o = { (__bf16)v.x, (__bf16)v.y, (__bf16)v.z, (__bf16)v.w };
  *(bf16x4*)(out + i) = o;
}

// ---------------- fp32 [R][C] -> bf16 [C][R] transpose-convert ----------------
__global__ __launch_bounds__(256)
void transpose_cvt(const float* __restrict__ in, __bf16* __restrict__ out, int R, int C) {
  __shared__ float tile[32][33];
  int tx = threadIdx.x, ty = threadIdx.y;
  int c0 = blockIdx.x * 32, r0 = blockIdx.y * 32;
#pragma unroll
  for (int j = 0; j < 4; j++)
    tile[ty + 8 * j][tx] = in[(size_t)(r0 + ty + 8 * j) * C + c0 + tx];
  __syncthreads();
#pragma unroll
  for (int j = 0; j < 4; j++)
    out[(size_t)(c0 + ty + 8 * j) * R + r0 + tx] = (__bf16)tile[tx][ty + 8 * j];
}

// ---------------- bf16 [R][Csub] (ld=ldin) -> bf16 [Csub][R] (ld=ldout) ----------------
__global__ __launch_bounds__(256)
void transpose_bf16(const __bf16* __restrict__ in, __bf16* __restrict__ out,
                    int R, int C, int ldin, int ldout) {
  __shared__ __bf16 tile[32][33];
  int tx = threadIdx.x, ty = threadIdx.y;
  int c0 = blockIdx.x * 32, r0 = blockIdx.y * 32;
#pragma unroll
  for (int j = 0; j < 4; j++)
    tile[ty + 8 * j][tx] = in[(size_t)(r0 + ty + 8 * j) * ldin + c0 + tx];
  __syncthreads();
#pragma unroll
  for (int j = 0; j < 4; j++)
    out[(size_t)(c0 + ty + 8 * j) * ldout + r0 + tx] = tile[tx][ty + 8 * j];
}

// ---------------- 4-phase GEMM: C[M][N] = A[M][K] * BT[N][K]^T + bias ----------------
// BM=256, BN=192 (MODE 0) / 128 (MODE 1), BK=64, 8 waves (2M x 4N).
// Per K-tile: 4 phases (fm-half x ks-half), each {ds_read; stage 1-3 chunks;
// barrier; setprio; MFMA; setprio; barrier}. A: 2 tile-buffers (chunk-ordered
// WAR-safe), B: 3 tile-buffers. Boundary wait: counted vmcnt(5/4), never 0
// until the last tile. Staged chunks get 5-8 phases of latency cover.
template <int MODE, int BN>
__global__ __launch_bounds__(512, 1)
void gemm_big(const __bf16* __restrict__ A, const __bf16* __restrict__ BT,
              const float* __restrict__ b0, const float* __restrict__ b1,
              const float* __restrict__ b2,
              __bf16* __restrict__ Cb, float* __restrict__ Cf,
              int M, int N, int K) {
  constexpr int FN = BN / 64;        // B 64-row chunks per tile = B frags per wave
  __shared__ __bf16 Alds[2 * 256 * 64];   // 64 KB: 2 tile-bufs x 4 chunks
  __shared__ __bf16 Blds[3 * BN * 64];    // 72/48 KB: 3 tile-bufs x FN chunks
  const int t = threadIdx.x;
  const int lane = t & 63, w = t >> 6;
  const int lr = lane & 15, lg = lane >> 4;
  const int wm = w >> 2, wn = w & 3;
  const int cpx = gridDim.x >> 3;
  const int swz = (blockIdx.x & 7) * cpx + (blockIdx.x >> 3);
  const int nbx = N / BN;
  const int m0 = (swz / nbx) * 256, n0 = (swz % nbx) * BN;
  const int scol = (((t & 7) ^ ((t >> 3) & 7)) << 3);

  const __bf16* Abase = A + (size_t)(m0 + (t >> 3)) * K + scol;
  const __bf16* Bbase = BT + (size_t)(n0 + (t >> 3)) * K + scol;

  auto stageA = [&](int tile, int c) {   // chunk c: rows c*64..c*64+63
    lds_load16(Abase + (size_t)(c * 64) * K + tile * 64,
               Alds + (tile & 1) * 16384 + c * 4096 + t * 8);
  };
  auto stageB = [&](int tile, int bi, int c) {
    lds_load16(Bbase + (size_t)(c * 64) * K + tile * 64,
               Blds + bi * (BN * 64) + c * 4096 + t * 8);
  };

  const f32x4 fz = {0.f, 0.f, 0.f, 0.f};
  f32x4 acc[8][FN];
#pragma unroll
  for (int fm = 0; fm < 8; fm++)
#pragma unroll
    for (int fn = 0; fn < FN; fn++) acc[fm][fn] = fz;

  // prologue: tile 0 full (oldest 4+FN loads), then tile 1 partial {c0, c2, B}
#pragma unroll
  for (int c = 0; c < 4; c++) stageA(0, c);
#pragma unroll
  for (int c = 0; c < FN; c++) stageB(0, 0, c);
  stageA(1, 0);
  stageA(1, 2);
#pragma unroll
  for (int c = 0; c < FN; c++) stageB(1, 1, c);

  int bcur = 0, bn1 = 1, bn2 = 2;  // B buffer of tile kt, kt+1, kt+2
  for (int kt = 0; kt < 32; kt++) {
    // boundary: tile kt's 4+FN loads are the oldest outstanding
    if (kt < 31) {
      if constexpr (FN == 3) asm volatile("s_waitcnt vmcnt(5)" ::: "memory");
      else                   asm volatile("s_waitcnt vmcnt(4)" ::: "memory");
    } else {
      asm volatile("s_waitcnt vmcnt(0)" ::: "memory");
    }
    __builtin_amdgcn_s_barrier();
    __builtin_amdgcn_sched_barrier(0);

    const __bf16* Ab = Alds + (kt & 1) * 16384;
    const __bf16* Bb = Blds + bcur * (BN * 64);
    v8bf16 bfr[2][FN];

    // ---- phase 1: fmh=0, ks=0 ----
    {
#pragma unroll
      for (int fn = 0; fn < FN; fn++)
        bfr[0][fn] = *(const v8bf16*)&Bb[sw64(wn * (BN / 4) + fn * 16 + lr, lg * 8)];
      v8bf16 af[4];
#pragma unroll
      for (int j = 0; j < 4; j++)
        af[j] = *(const v8bf16*)&Ab[sw64(wm * 128 + j * 16 + lr, lg * 8)];
      if (kt < 31) stageA(kt + 1, 1);
      __builtin_amdgcn_s_barrier();
      __builtin_amdgcn_sched_barrier(0);
      __builtin_amdgcn_s_setprio(1);
#pragma unroll
      for (int j = 0; j < 4; j++)
#pragma unroll
        for (int fn = 0; fn < FN; fn++)
          acc[j][fn] = __builtin_amdgcn_mfma_f32_16x16x32_bf16(af[j], bfr[0][fn], acc[j][fn], 0, 0, 0);
      __builtin_amdgcn_s_setprio(0);
      __builtin_amdgcn_sched_barrier(0);
      __builtin_amdgcn_s_barrier();
    }
    // ---- phase 2: fmh=0, ks=1 ----
    {
#pragma unroll
      for (int fn = 0; fn < FN; fn++)
        bfr[1][fn] = *(const v8bf16*)&Bb[sw64(wn * (BN / 4) + fn * 16 + lr, 32 + lg * 8)];
      v8bf16 af[4];
#pragma unroll
      for (int j = 0; j < 4; j++)
        af[j] = *(const v8bf16*)&Ab[sw64(wm * 128 + j * 16 + lr, 32 + lg * 8)];
      if (kt < 31) stageA(kt + 1, 3);
      __builtin_amdgcn_s_barrier();
      __builtin_amdgcn_sched_barrier(0);
      __builtin_amdgcn_s_setprio(1);
#pragma unroll
      for (int j = 0; j < 4; j++)
#pragma unroll
        for (int fn = 0; fn < FN; fn++)
          acc[j][fn] = __builtin_amdgcn_mfma_f32_16x16x32_bf16(af[j], bfr[1][fn], acc[j][fn], 0, 0, 0);
      __builtin_amdgcn_s_setprio(0);
      __builtin_amdgcn_sched_barrier(0);
      __builtin_amdgcn_s_barrier();
    }
    // ---- phase 3: fmh=1, ks=0 (A rows 0-63/128-191 now fully read -> stage over them) ----
    {
      v8bf16 af[4];
#pragma unroll
      for (int j = 0; j < 4; j++)
        af[j] = *(const v8bf16*)&Ab[sw64(wm * 128 + 64 + j * 16 + lr, lg * 8)];
      if (kt < 30) { stageA(kt + 2, 0); stageB(kt + 2, bn2, 0); }
      __builtin_amdgcn_s_barrier();
      __builtin_amdgcn_sched_barrier(0);
      __builtin_amdgcn_s_setprio(1);
#pragma unroll
      for (int j = 0; j < 4; j++)
#pragma unroll
        for (int fn = 0; fn < FN; fn++)
          acc[4 + j][fn] = __builtin_amdgcn_mfma_f32_16x16x32_bf16(af[j], bfr[0][fn], acc[4 + j][fn], 0, 0, 0);
      __builtin_amdgcn_s_setprio(0);
      __builtin_amdgcn_sched_barrier(0);
      __builtin_amdgcn_s_barrier();
    }
    // ---- phase 4: fmh=1, ks=1 ----
    {
      v8bf16 af[4];
#pragma unroll
      for (int j = 0; j < 4; j++)
        af[j] = *(const v8bf16*)&Ab[sw64(wm * 128 + 64 + j * 16 + lr, 32 + lg * 8)];
      if (kt < 30) {
        stageA(kt + 2, 2);
        stageB(kt + 2, bn2, 1);
        if constexpr (FN == 3) stageB(kt + 2, bn2, 2);
      }
      __builtin_amdgcn_s_barrier();
      __builtin_amdgcn_sched_barrier(0);
      __builtin_amdgcn_s_setprio(1);
#pragma unroll
      for (int j = 0; j < 4; j++)
#pragma unroll
        for (int fn = 0; fn < FN; fn++)
          acc[4 + j][fn] = __builtin_amdgcn_mfma_f32_16x16x32_bf16(af[j], bfr[1][fn], acc[4 + j][fn], 0, 0, 0);
      __builtin_amdgcn_s_setprio(0);
      __builtin_amdgcn_sched_barrier(0);
    }

    int tmp = bcur; bcur = bn1; bn1 = bn2; bn2 = tmp;
  }

#pragma unroll
  for (int fn = 0; fn < FN; fn++) {
    int col = n0 + wn * (BN / 4) + fn * 16 + lr;
    float bias, scale = 1.0f;
    if (MODE == 0) {
      if (col < 2048)      { bias = b0[col];        scale = QSCALE; }
      else if (col < 2560) { bias = b1[col - 2048]; }
      else                 { bias = b2[col - 2560]; }
    } else {
      bias = b0[col];
    }
#pragma unroll
    for (int fm = 0; fm < 8; fm++)
#pragma unroll
      for (int r = 0; r < 4; r++) {
        int row = m0 + wm * 128 + fm * 16 + lg * 4 + r;
        float v = acc[fm][fn][r] + bias;
        if (MODE == 0) Cb[(size_t)row * N + col] = (__bf16)(v * scale);
        else           Cf[(size_t)row * N + col] = v;
      }
  }
}

// ---------------- GQA flash attention (8 waves x 32 q, r7 best-measured) ----------------
__global__ __launch_bounds__(512, 2)
void attn_kernel(const __bf16* __restrict__ QKV, const __bf16* __restrict__ VT,
                 __bf16* __restrict__ ctx) {
  __shared__ __bf16 smem[26624];
  const int t = threadIdx.x;
  const int lane = t & 63, w = t >> 6;
  const int lr = lane & 15, lg = lane >> 4;
  const int flat = blockIdx.y * 8 + blockIdx.x;
  const int swz = (flat & 7) * 64 + (flat >> 3);
  const int qt = swz & 7, bh = swz >> 3;
  const int b = bh >> 5, h = bh & 31, g = h >> 2;
  const int q0 = qt * 256;
  const int scol = (((t & 7) ^ ((t >> 3) & 7)) << 3);

  v8bf16 qa[2][2];
#pragma unroll
  for (int mi = 0; mi < 2; mi++)
#pragma unroll
    for (int dk2 = 0; dk2 < 2; dk2++)
      qa[mi][dk2] = *(const v8bf16*)(QKV +
          (size_t)(b * S_LEN + q0 + w * 32 + mi * 16 + lr) * NQKV + h * DK + dk2 * 32 + lg * 8);

  const __bf16* kp = QKV + (size_t)(b * S_LEN + (t >> 3)) * NQKV + D_MODEL + g * DK + scol;
  const __bf16* vp = VT + (size_t)(g * DK + (t >> 3)) * NTOK + b * S_LEN + scol;

  lds_load16(kp, smem + t * 8);
  lds_load16(vp, smem + 4096 + t * 8);
  __syncthreads();

  const int kloff0 = lr * 64 + ((lg * 8) ^ ((lr & 7) << 3));
  const int kloff1 = lr * 64 + ((32 + lg * 8) ^ ((lr & 7) << 3));
  __bf16* Pw = smem + 16384 + w * 1280;  // [32][40]

  const __bf16 one1 = (__bf16)1.0f;
  const v8bf16 ones = { one1, one1, one1, one1, one1, one1, one1, one1 };
  const f32x4 fz = {0.f, 0.f, 0.f, 0.f};
  f32x4 o[2][4], o_sum[2];
  o_sum[0] = fz; o_sum[1] = fz;
#pragma unroll
  for (int mi = 0; mi < 2; mi++)
#pragma unroll
    for (int nd = 0; nd < 4; nd++) o[mi][nd] = fz;

#pragma unroll 2
  for (int kt = 0; kt < 32; kt++) {
    if (kt < 31) {
      __bf16* nb = smem + ((kt & 1) ^ 1) * 8192;
      lds_load16(kp + (size_t)64 * NQKV, nb + t * 8);
      lds_load16(vp + 64, nb + 4096 + t * 8);
      kp += (size_t)64 * NQKV;
      vp += 64;
    }
    const __bf16* Kb = smem + (kt & 1) * 8192;
    const __bf16* k0 = Kb + kloff0;
    const __bf16* k1 = Kb + kloff1;

    f32x4 st[4][2];
#pragma unroll
    for (int ni = 0; ni < 4; ni++) { st[ni][0] = fz; st[ni][1] = fz; }
    __builtin_amdgcn_s_setprio(1);
#pragma unroll
    for (int ni = 0; ni < 4; ni++) {
      v8bf16 kb = *(const v8bf16*)(k0 + ni * 1024);
      st[ni][0] = __builtin_amdgcn_mfma_f32_16x16x32_bf16(kb, qa[0][0], st[ni][0], 0, 0, 0);
      st[ni][1] = __builtin_amdgcn_mfma_f32_16x16x32_bf16(kb, qa[1][0], st[ni][1], 0, 0, 0);
    }
#pragma unroll
    for (int ni = 0; ni < 4; ni++) {
      v8bf16 kb = *(const v8bf16*)(k1 + ni * 1024);
      st[ni][0] = __builtin_amdgcn_mfma_f32_16x16x32_bf16(kb, qa[0][1], st[ni][0], 0, 0, 0);
      st[ni][1] = __builtin_amdgcn_mfma_f32_16x16x32_bf16(kb, qa[1][1], st[ni][1], 0, 0, 0);
    }
    __builtin_amdgcn_s_setprio(0);

#pragma unroll
    for (int ks = 0; ks < 2; ks++) {
      const __bf16* vbase = (ks ? k1 : k0) + 4096;
#pragma unroll
      for (int mi = 0; mi < 2; mi++)
#pragma unroll
        for (int ni2 = 0; ni2 < 2; ni2++) {
          f32x4 sv = st[2 * ks + ni2][mi];
          bf16x4 pk = { (__bf16)exp2f(sv[0]), (__bf16)exp2f(sv[1]),
                        (__bf16)exp2f(sv[2]), (__bf16)exp2f(sv[3]) };
          *(bf16x4*)(Pw + (mi * 16 + lr) * 40 + ni2 * 16 + lg * 4) = pk;
        }
      v8bf16 pa0 = *(const v8bf16*)(Pw + lr * 40 + lg * 8);
      v8bf16 pa1 = *(const v8bf16*)(Pw + (16 + lr) * 40 + lg * 8);
      __builtin_amdgcn_s_setprio(1);
#pragma unroll
      for (int nd = 0; nd < 4; nd++) {
        v8bf16 vb = *(const v8bf16*)(vbase + nd * 1024);
        o[0][nd] = __builtin_amdgcn_mfma_f32_16x16x32_bf16(pa0, vb, o[0][nd], 0, 0, 0);
        o[1][nd] = __builtin_amdgcn_mfma_f32_16x16x32_bf16(pa1, vb, o[1][nd], 0, 0, 0);
      }
      o_sum[0] = __builtin_amdgcn_mfma_f32_16x16x32_bf16(pa0, ones, o_sum[0], 0, 0, 0);
      o_sum[1] = __builtin_amdgcn_mfma_f32_16x16x32_bf16(pa1, ones, o_sum[1], 0, 0, 0);
      __builtin_amdgcn_s_setprio(0);
    }

    __syncthreads();
  }

#pragma unroll
  for (int mi = 0; mi < 2; mi++)
#pragma unroll
    for (int r = 0; r < 4; r++) {
      float inv = 1.0f / o_sum[mi][r];
      int row = b * S_LEN + q0 + w * 32 + mi * 16 + lg * 4 + r;
#pragma unroll
      for (int nd = 0; nd < 4; nd++)
        ctx[(size_t)row * D_MODEL + h * DK + nd * 16 + lr] = (__bf16)(o[mi][nd][r] * inv);
    }
}

extern "C" void kernel_launch(void* const* d_in, const int* in_sizes, int n_in,
                              void* d_out, int out_size, void* d_ws, size_t ws_size,
                              hipStream_t stream) {
  (void)in_sizes; (void)n_in; (void)out_size; (void)ws_size;
  const float* x  = (const float*)d_in[0];
  const float* wq = (const float*)d_in[1];
  const float* bq = (const float*)d_in[2];
  const float* wk = (const float*)d_in[3];
  const float* bk = (const float*)d_in[4];
  const float* wv = (const float*)d_in[5];
  const float* bv = (const float*)d_in[6];
  const float* wo = (const float*)d_in[7];
  const float* bo = (const float*)d_in[8];

  char* ws = (char*)d_ws;
  __bf16* xb    = (__bf16*)(ws);                 // [4096][2048]   16 MB
  __bf16* wqkvT = (__bf16*)(ws + 16777216);      // [3072][2048]   12 MB
  __bf16* woT   = (__bf16*)(ws + 29360128);      // [2048][2048]    8 MB
  __bf16* QKVb  = (__bf16*)(ws + 37748736);      // [4096][3072]   24 MB
  __bf16* VbT   = (__bf16*)(ws + 62914560);      // [512][4096]     4 MB
  __bf16* ctx   = (__bf16*)(ws + 67108864);      // [4096][2048]   16 MB

  dim3 tb(32, 8);
  cvt_f32_bf16<<<8192, 256, 0, stream>>>(x, xb, NTOK * D_MODEL);
  transpose_cvt<<<dim3(64, 64), tb, 0, stream>>>(wq, wqkvT, 2048, 2048);
  transpose_cvt<<<dim3(16, 64), tb, 0, stream>>>(wk, wqkvT + 2048 * 2048, 2048, 512);
  transpose_cvt<<<dim3(16, 64), tb, 0, stream>>>(wv, wqkvT + 2560 * 2048, 2048, 512);
  transpose_cvt<<<dim3(64, 64), tb, 0, stream>>>(wo, woT, 2048, 2048);

  gemm_big<0, 192><<<dim3(256), 512, 0, stream>>>(xb, wqkvT, bq, bk, bv,
                                                  QKVb, nullptr, NTOK, NQKV, 2048);
  transpose_bf16<<<dim3(16, 128), tb, 0, stream>>>(QKVb + 2560, VbT, 4096, 512, 3072, 4096);
  attn_kernel<<<dim3(8, 64), 512, 0, stream>>>(QKVb, VbT, ctx);
  gemm_big<1, 128><<<dim3(256), 512, 0, stream>>>(ctx, woT, bo, nullptr, nullptr,
                                                  nullptr, (float*)d_out, NTOK, 2048, 2048);
}